// Round 11
// baseline (154.885 us; speedup 1.0000x reference)
//
#include <hip/hip_runtime.h>

// Problem: B=8, C=512, H*W=1024 spatial, 8 heads x d=64, GROUPS=32.
// Pipeline: prep(GN+weights) -> QKV GEMM -> V-transpose -> attn -> out-proj.
// Round 23: attn rewritten in the m214/HK 32x32-MFMA structure. QK and PV
// use mfma_f32_32x32x16_bf16 (m = lane&31 -> P-row LANE-LOCAL). The pt4 LDS
// round-trip is replaced by 16 cvt_pk + 8 v_permlane32_swap (T12): one swap
// of u[4k+par]<->u[4k+2+par] fills PV A-frag words w,w+2 for both lane
// halves. MFMA/iter 36->20, LDS ops/iter 28->16, LDS 48->32KB. l via
// ones-MFMA (D-layout matches acc_o -> element-wise invl). R22's single-slot
// pt4 reverted (absmax anomaly). Other kernels unchanged.

typedef __attribute__((ext_vector_type(8))) short bf16x8;   // 8 bf16 in 4 VGPRs
typedef __attribute__((ext_vector_type(4))) short bf16x4;   // 4 bf16 (8B)
typedef __attribute__((ext_vector_type(4))) float f32x4;
typedef __attribute__((ext_vector_type(16))) float f32x16;

#define NB 8
#define NC 512
#define HW 1024
#define NHEAD 8
#define DHEAD 64
#define GROUPS 32
#define CPG 16          // channels per group
#define QKV_N 1536

// global -> LDS direct copy, 16B per lane; lds base must be wave-uniform.
#define GLL16(gaddr, ldsaddr)                                                  \
    __builtin_amdgcn_global_load_lds(                                          \
        (const __attribute__((address_space(1))) unsigned*)(gaddr),            \
        (__attribute__((address_space(3))) unsigned*)(ldsaddr), 16, 0, 0)

// Scratch in device globals.
__device__ alignas(64) short g_xn[(size_t)8192 * 512];      // GN out, pixel-major [bs][c]
__device__ alignas(64) short g_qkv[(size_t)8192 * 1536];    // QKV GEMM out [bs][3C]
__device__ alignas(64) short g_vt[(size_t)64 * 64 * 1024];  // V^T [b*8+h][d][s]
__device__ alignas(64) short g_attno[(size_t)8192 * 512];   // attention out [bs][c]
__device__ alignas(64) short g_wqkv[(size_t)1536 * 512];    // w_qkv as bf16 [o][c]
__device__ alignas(64) short g_wout[(size_t)512 * 512];     // w_out as bf16 [o][c]

__device__ __forceinline__ float b2f(short h) {
    union { unsigned u; float f; } v;
    v.u = ((unsigned)(unsigned short)h) << 16;
    return v.f;
}
__device__ __forceinline__ short f2b(float f) {
    union { float f; unsigned u; } v;
    v.f = f;
    unsigned r = v.u + 0x7fff + ((v.u >> 16) & 1);   // RNE
    return (short)(r >> 16);
}

// ---------------------------------------------------------------------------
// Kernel 1: prep = GroupNorm (blocks 0..255) + weight conversion (256..319).
// ---------------------------------------------------------------------------
__global__ __launch_bounds__(256) void prep_kernel(
    const float* __restrict__ x, const float* __restrict__ gamma,
    const float* __restrict__ beta, const float* __restrict__ wqkv,
    const float* __restrict__ wout) {
    int tid = threadIdx.x;
    if (blockIdx.x >= 256) {                 // ---- weight conversion part
        int wb = blockIdx.x - 256;           // 0..63
        for (int i = wb * 256 + tid; i < 1536 * 512; i += 64 * 256) {
            float v = wqkv[i];
            // Q rows: fold 1/sqrt(d) AND log2(e) so attn P = 2^S (raw v_exp).
            if (i < 512 * 512) v *= 0.18033688011112042f;
            g_wqkv[i] = f2b(v);
        }
        for (int i = wb * 256 + tid; i < 512 * 512; i += 64 * 256)
            g_wout[i] = f2b(wout[i]);
        return;
    }
    // ---- GroupNorm part
    int b = blockIdx.x >> 5, g = blockIdx.x & 31;
    __shared__ alignas(16) short tile[CPG][HW];          // 32 KB
    __shared__ float red[2][4];
    __shared__ float sg[CPG], sb[CPG];
    if (tid < CPG) {
        int cg = g * CPG + tid;
        sg[tid] = gamma[cg];
        sb[tid] = beta[cg];
    }
    const float* xb = x + (size_t)b * NC * HW + (size_t)g * CPG * HW;
    float s1 = 0.f, s2 = 0.f;
    #pragma unroll
    for (int it = 0; it < 8; it++) {
        int idx = tid + it * 256;
        f32x4 v0 = *(const f32x4*)(xb + idx * 8);
        f32x4 v1 = *(const f32x4*)(xb + idx * 8 + 4);
        bf16x8 w;
        #pragma unroll
        for (int j = 0; j < 4; j++) {
            s1 += v0[j] + v1[j]; s2 += v0[j] * v0[j] + v1[j] * v1[j];
            w[j] = f2b(v0[j]); w[j + 4] = f2b(v1[j]);
        }
        *(bf16x8*)(&((short*)tile)[idx * 8]) = w;
    }
    #pragma unroll
    for (int off = 32; off; off >>= 1) { s1 += __shfl_xor(s1, off); s2 += __shfl_xor(s2, off); }
    int wid = tid >> 6;
    if ((tid & 63) == 0) { red[0][wid] = s1; red[1][wid] = s2; }
    __syncthreads();
    float t1 = red[0][0] + red[0][1] + red[0][2] + red[0][3];
    float t2 = red[1][0] + red[1][1] + red[1][2] + red[1][3];
    float mean = t1 * (1.f / 16384.f);
    float var  = t2 * (1.f / 16384.f) - mean * mean;
    float inv  = rsqrtf(var + 1e-5f);
    #pragma unroll
    for (int p = 0; p < 4; p++) {
        int s = tid * 4 + p;
        bf16x8 pk0, pk1;
        #pragma unroll
        for (int cc = 0; cc < 8; cc++) {
            pk0[cc] = f2b((b2f(tile[cc][s])     - mean) * inv * sg[cc]     + sb[cc]);
            pk1[cc] = f2b((b2f(tile[cc + 8][s]) - mean) * inv * sg[cc + 8] + sb[cc + 8]);
        }
        size_t dst = ((size_t)(b * HW + s)) * NC + g * CPG;
        *(bf16x8*)(g_xn + dst)     = pk0;
        *(bf16x8*)(g_xn + dst + 8) = pk1;
    }
}

// ---------------------------------------------------------------------------
// Kernel 2: QKV GEMM. M=8192 N=1536 K=512. BK=64 + XOR swizzle (r18).
// ---------------------------------------------------------------------------
__global__ __launch_bounds__(256) void gemm_qkv() {
    const int K = NC;
    int tid = threadIdx.x, lane = tid & 63, wid = tid >> 6;
    int quad = lane >> 4, l15 = lane & 15;
    int row0 = blockIdx.x * 128;
    int col0 = blockIdx.y * 128;
    __shared__ alignas(16) short sa[128 * 64];   // 16 KB, granule-swizzled
    __shared__ alignas(16) short sbuf[128 * 64]; // 16 KB, granule-swizzled
    int r_lo = lane >> 3;                        // row within 8-row stripe
    int s_log = (lane & 7) ^ r_lo;               // pre-swizzled source granule
    int swz = l15 & 7;                           // fragment-read swizzle
    const short* ga = g_xn   + (size_t)(row0 + wid * 32 + r_lo) * K + s_log * 8;
    const short* gb = g_wqkv + (size_t)(col0 + wid * 32 + r_lo) * K + s_log * 8;
    int mw = (wid >> 1) * 64, nw = (wid & 1) * 64;
    f32x4 acc[4][4] = {};
    for (int k = 0; k < K; k += 64) {
        #pragma unroll
        for (int c = 0; c < 4; c++) {
            GLL16(ga + (size_t)(c * 8) * K + k, &sa[(wid * 32 + c * 8) * 64]);
            GLL16(gb + (size_t)(c * 8) * K + k, &sbuf[(wid * 32 + c * 8) * 64]);
        }
        __syncthreads();
        bf16x8 af0[4], af1[4], bf0[4], bf1[4];
        #pragma unroll
        for (int m = 0; m < 4; m++) {
            int row = mw + m * 16 + l15;
            af0[m] = *(const bf16x8*)&sa[row * 64 + ((quad ^ swz) * 8)];
            af1[m] = *(const bf16x8*)&sa[row * 64 + (((4 + quad) ^ swz) * 8)];
        }
        #pragma unroll
        for (int n = 0; n < 4; n++) {
            int row = nw + n * 16 + l15;
            bf0[n] = *(const bf16x8*)&sbuf[row * 64 + ((quad ^ swz) * 8)];
            bf1[n] = *(const bf16x8*)&sbuf[row * 64 + (((4 + quad) ^ swz) * 8)];
        }
        #pragma unroll
        for (int m = 0; m < 4; m++)
            #pragma unroll
            for (int n = 0; n < 4; n++) {
                acc[m][n] = __builtin_amdgcn_mfma_f32_16x16x32_bf16(af0[m], bf0[n], acc[m][n], 0, 0, 0);
                acc[m][n] = __builtin_amdgcn_mfma_f32_16x16x32_bf16(af1[m], bf1[n], acc[m][n], 0, 0, 0);
            }
        __syncthreads();
    }
    #pragma unroll
    for (int m = 0; m < 4; m++)
        #pragma unroll
        for (int n = 0; n < 4; n++)
            #pragma unroll
            for (int r = 0; r < 4; r++) {
                int row = row0 + mw + m * 16 + quad * 4 + r;
                int col = col0 + nw + n * 16 + l15;
                g_qkv[(size_t)row * QKV_N + col] = f2b(acc[m][n][r]);
            }
}

// ---------------------------------------------------------------------------
// Kernel 2b: V transpose. g_qkv V-part [bs][c] -> g_vt[bh][d][s].
// ---------------------------------------------------------------------------
__global__ __launch_bounds__(256) void transpose_v() {
    int bh = blockIdx.x & 63, st = blockIdx.x >> 6;     // grid 1024
    int b = bh >> 3, h = bh & 7;
    int tid = threadIdx.x;
    __shared__ alignas(16) short tile[64][72];
    int s0 = st * 64;
    #pragma unroll
    for (int cc = 0; cc < 2; cc++) {
        int idx = tid + cc * 256;
        int s = idx >> 3, dc = idx & 7;
        *(bf16x8*)&tile[s][dc * 8] =
            *(const bf16x8*)(g_qkv + ((size_t)(b * HW + s0 + s)) * QKV_N + 1024 + h * DHEAD + dc * 8);
    }
    __syncthreads();
    #pragma unroll
    for (int cc = 0; cc < 2; cc++) {
        int idx = tid + cc * 256;
        int d = idx & 63, sc = idx >> 6;                // sc wave-uniform
        bf16x8 o;
        #pragma unroll
        for (int j = 0; j < 8; j++) o[j] = tile[sc * 8 + j][d];
        *(bf16x8*)(g_vt + ((size_t)(bh * 64 + d)) * HW + s0 + sc * 8) = o;
    }
}

// ---------------------------------------------------------------------------
// Kernel 3: flash attention, 32x32-MFMA structure (r23).
// Grid 512: bh = blk&63 (XCD L2 sharing), qt = blk>>6 (0..7).
// 4 waves x 32 q-rows. QK: z[th] = K-frag x Q-frag (32x32x16), D-layout
// row=(reg&3)+8*(reg>>2)+4*hl, col=m=lane&31 -> P lane-local. exp2 ->
// cvt_pk pairs u[th][p] (t-base (p>>1)*8+(p&1)*2+4*hl) -> 8 permlane32_swap
// build PV A-frags ap[ks] (t = ks*16+hl*8+jj). l/PV via 32x32 MFMA.
// LDS: kt 2x8 + vt 2x8 = 32KB. No pt4.
// ---------------------------------------------------------------------------
__global__ __launch_bounds__(256) void attn_kernel() {
    int bh = blockIdx.x & 63, qt = blockIdx.x >> 6;
    int b = bh >> 3, h = bh & 7;
    int tid = threadIdx.x, lane = tid & 63, wid = tid >> 6;
    int l31 = lane & 31, hl = lane >> 5;
    __shared__ alignas(16) short kt[2][64 * 64];    // 8 KB each, swizzled
    __shared__ alignas(16) short vt[2][64 * 64];    // 8 KB each, swizzled
    int qrow0 = qt * 128 + wid * 32;

    // Q = B-operand: B[k=d][j=m]: lane j=l31, k = ks*16 + hl*8 + jj.
    const short* qb = g_qkv + ((size_t)(b * HW + qrow0 + l31)) * QKV_N + h * DHEAD + hl * 8;
    bf16x8 aq[4];
    #pragma unroll
    for (int ks = 0; ks < 4; ks++) aq[ks] = *(const bf16x8*)(qb + ks * 16);

    f32x16 acc_o0 = {}, acc_o1 = {}, acc_l = {};
    bf16x8 vone;
    #pragma unroll
    for (int j = 0; j < 8; j++) vone[j] = (short)0x3f80;   // bf16 1.0

    int r_lo = lane >> 3;
    int s_log = (lane & 7) ^ r_lo;

    auto stage = [&](int it, int bufi) {
        int t0 = it * 64;
        #pragma unroll
        for (int c = 0; c < 2; c++) {
            int r = wid * 16 + c * 8 + r_lo;
            GLL16(g_qkv + ((size_t)(b * HW + t0 + r)) * QKV_N + 512 + h * DHEAD + s_log * 8,
                  &kt[bufi][(wid * 16 + c * 8) * 64]);
            GLL16(g_vt + ((size_t)(bh * 64 + r)) * HW + t0 + s_log * 8,
                  &vt[bufi][(wid * 16 + c * 8) * 64]);
        }
    };

    stage(0, 0);
    __syncthreads();
    for (int it = 0; it < 16; it++) {
        int cur = it & 1;
        if (it < 15) stage(it + 1, cur ^ 1);        // prefetch into alt buffer
        // ---- QK: z[th] = sum_ks K[t(th)][d] * Q[m][d], 32x32x16 ----
        f32x16 z0 = {}, z1 = {};
        #pragma unroll
        for (int ks = 0; ks < 4; ks++) {
            int g0 = ks * 2 + hl;                    // logical d-granule
            int rowa = l31;                          // t 0..31
            bf16x8 k0 = *(const bf16x8*)&kt[cur][rowa * 64 + ((g0 ^ (rowa & 7)) * 8)];
            z0 = __builtin_amdgcn_mfma_f32_32x32x16_bf16(k0, aq[ks], z0, 0, 0, 0);
            int rowb = 32 + l31;                     // t 32..63
            bf16x8 k1 = *(const bf16x8*)&kt[cur][rowb * 64 + ((g0 ^ (rowb & 7)) * 8)];
            z1 = __builtin_amdgcn_mfma_f32_32x32x16_bf16(k1, aq[ks], z1, 0, 0, 0);
        }
        // ---- P = 2^z, cvt_pk into u[th][p] (t-pair base (p>>1)*8+(p&1)*2+4hl) ----
        unsigned u0[8], u1[8];
        #pragma unroll
        for (int p = 0; p < 8; p++) {
            float e0, e1, e2, e3;
            asm("v_exp_f32 %0, %1" : "=v"(e0) : "v"(z0[2 * p]));
            asm("v_exp_f32 %0, %1" : "=v"(e1) : "v"(z0[2 * p + 1]));
            asm("v_exp_f32 %0, %1" : "=v"(e2) : "v"(z1[2 * p]));
            asm("v_exp_f32 %0, %1" : "=v"(e3) : "v"(z1[2 * p + 1]));
            asm("v_cvt_pk_bf16_f32 %0, %1, %2" : "=v"(u0[p]) : "v"(e0), "v"(e1));
            asm("v_cvt_pk_bf16_f32 %0, %1, %2" : "=v"(u1[p]) : "v"(e2), "v"(e3));
        }
        // ---- 8 permlane32_swap -> PV A-frags ap[ks'] (t = ks'*16+hl*8+jj) ----
        // swap(x,y): lanes<32 end with both halves of x, lanes>=32 both of y.
        bf16x8 ap[4];
        #pragma unroll
        for (int th = 0; th < 2; th++) {
            #pragma unroll
            for (int ks1 = 0; ks1 < 2; ks1++) {
                unsigned x0 = th ? u1[4 * ks1]     : u0[4 * ks1];
                unsigned y0 = th ? u1[4 * ks1 + 2] : u0[4 * ks1 + 2];
                unsigned x1 = th ? u1[4 * ks1 + 1] : u0[4 * ks1 + 1];
                unsigned y1 = th ? u1[4 * ks1 + 3] : u0[4 * ks1 + 3];
                asm("v_permlane32_swap_b32 %0, %1" : "+v"(x0), "+v"(y0));
                asm("v_permlane32_swap_b32 %0, %1" : "+v"(x1), "+v"(y1));
                union { unsigned w[4]; bf16x8 v; } pa;
                pa.w[0] = x0; pa.w[1] = x1; pa.w[2] = y0; pa.w[3] = y1;
                ap[th * 2 + ks1] = pa.v;
            }
        }
        // ---- l += P * ones (D-layout matches acc_o: element-wise later) ----
        #pragma unroll
        for (int ks = 0; ks < 4; ks++)
            acc_l = __builtin_amdgcn_mfma_f32_32x32x16_bf16(ap[ks], vone, acc_l, 0, 0, 0);
        // ---- O += P V (B = V^T: lane j=d=l31, k = t = ks*16+hl*8+jj) ----
        #pragma unroll
        for (int ks = 0; ks < 4; ks++) {
            int gt = ks * 2 + hl;                    // logical t-granule
            int rowd0 = l31;                         // d 0..31
            bf16x8 bv0 = *(const bf16x8*)&vt[cur][rowd0 * 64 + ((gt ^ (rowd0 & 7)) * 8)];
            acc_o0 = __builtin_amdgcn_mfma_f32_32x32x16_bf16(ap[ks], bv0, acc_o0, 0, 0, 0);
            int rowd1 = 32 + l31;                    // d 32..63
            bf16x8 bv1 = *(const bf16x8*)&vt[cur][rowd1 * 64 + ((gt ^ (rowd1 & 7)) * 8)];
            acc_o1 = __builtin_amdgcn_mfma_f32_32x32x16_bf16(ap[ks], bv1, acc_o1, 0, 0, 0);
        }
        __syncthreads();   // drains prefetch GLLs + all tile reads
    }
    // Epilogue: m = (r&3)+8*(r>>2)+4*hl; l in acc_l[r] (same layout).
    #pragma unroll
    for (int r = 0; r < 16; r++) {
        int m = (r & 3) + 8 * (r >> 2) + 4 * hl;
        float invl = 1.f / acc_l[r];
        size_t row = (size_t)(b * HW + qrow0 + m);
        g_attno[row * NC + h * DHEAD + l31]      = f2b(acc_o0[r] * invl);
        g_attno[row * NC + h * DHEAD + 32 + l31] = f2b(acc_o1[r] * invl);
    }
}

// ---------------------------------------------------------------------------
// Kernel 4: out-proj GEMM + residual, m97 structure. (R16 version)
// ---------------------------------------------------------------------------
__global__ __launch_bounds__(256) void gemm_out(
    const float* __restrict__ xres, float* __restrict__ out) {
    const int K = NC;
    int tid = threadIdx.x, lane = tid & 63, wid = tid >> 6;
    int quad = lane >> 4, l15 = lane & 15;
    int row0 = blockIdx.x * 128;   // o
    int col0 = blockIdx.y * 128;   // bs
    __shared__ alignas(16) short sa[128 * 32];
    __shared__ alignas(16) short sbuf[128 * 32];
    int srow = wid * 32 + (lane >> 2);
    int scol = (lane & 3) * 8;
    const short* ga = g_wout  + (size_t)(row0 + srow) * K + scol;
    const short* gb = g_attno + (size_t)(col0 + srow) * K + scol;
    short* la = sa   + wid * 1024;
    short* lb = sbuf + wid * 1024;
    int mw = (wid >> 1) * 64, nw = (wid & 1) * 64;
    f32x4 acc[4][4] = {};
    for (int k = 0; k < K; k += 32) {
        GLL16(ga + k, la);
        GLL16(ga + (size_t)16 * K + k, la + 512);
        GLL16(gb + k, lb);
        GLL16(gb + (size_t)16 * K + k, lb + 512);
        __syncthreads();
        bf16x8 af[4], bfv[4];
        #pragma unroll
        for (int m = 0; m < 4; m++) af[m]  = *(const bf16x8*)&sa[(mw + m * 16 + l15) * 32 + quad * 8];
        #pragma unroll
        for (int n = 0; n < 4; n++) bfv[n] = *(const bf16x8*)&sbuf[(nw + n * 16 + l15) * 32 + quad * 8];
        #pragma unroll
        for (int m = 0; m < 4; m++)
            #pragma unroll
            for (int n = 0; n < 4; n++)
                acc[m][n] = __builtin_amdgcn_mfma_f32_16x16x32_bf16(af[m], bfv[n], acc[m][n], 0, 0, 0);
        __syncthreads();
    }
    #pragma unroll
    for (int m = 0; m < 4; m++)
        #pragma unroll
        for (int n = 0; n < 4; n++)
            #pragma unroll
            for (int r = 0; r < 4; r++) {
                int o  = row0 + mw + m * 16 + quad * 4 + r;
                int bs = col0 + nw + n * 16 + l15;
                size_t addr = (size_t)(bs >> 10) * ((size_t)NC * HW) + (size_t)o * HW + (bs & 1023);
                out[addr] = acc[m][n][r] + xres[addr];
            }
}

// ---------------------------------------------------------------------------
extern "C" void kernel_launch(void* const* d_in, const int* in_sizes, int n_in,
                              void* d_out, int out_size, void* d_ws, size_t ws_size,
                              hipStream_t stream) {
    const float* x     = (const float*)d_in[0];
    const float* gamma = (const float*)d_in[1];
    const float* beta  = (const float*)d_in[2];
    const float* wqkv  = (const float*)d_in[3];
    const float* wout  = (const float*)d_in[4];
    float* out = (float*)d_out;

    prep_kernel<<<dim3(320), dim3(256), 0, stream>>>(x, gamma, beta, wqkv, wout);
    gemm_qkv<<<dim3(64, 12), dim3(256), 0, stream>>>();
    transpose_v<<<dim3(1024), dim3(256), 0, stream>>>();
    attn_kernel<<<dim3(512), dim3(256), 0, stream>>>();
    gemm_out<<<dim3(4, 64), dim3(256), 0, stream>>>(x, out);
}

// Round 13
// 150.978 us; speedup vs baseline: 1.0259x; 1.0259x over previous
//
#include <hip/hip_runtime.h>

// Problem: B=8, C=512, H*W=1024 spatial, 8 heads x d=64, GROUPS=32.
// Pipeline: prep(GN+weights) -> QKV GEMM -> V-transpose -> attn -> out-proj.
// Round 25: RESUBMIT of R24 (bench infra failed twice; no measurement was
// taken). attn = R23 32x32-MFMA structure + R19 T15 double-pipeline.
// P lives in regs (ap_cur/ap_next) -- no pt4, no WAR trick (R22's absmax
// anomaly impossible). Body(it): bv(it)->regs, sync, stage(it+2,cur),
// QK(it+1) from kt[alt], exp/swap -> ap_next (VALU interleaves with
// following MFMAs), l+PV(it) from ap_cur. Both levers validated separately
// (T15: -3.4us in R19; 32x32: clean in R23); first time combined.
// Other kernels = R23 verbatim.

typedef __attribute__((ext_vector_type(8))) short bf16x8;   // 8 bf16 in 4 VGPRs
typedef __attribute__((ext_vector_type(4))) short bf16x4;   // 4 bf16 (8B)
typedef __attribute__((ext_vector_type(4))) float f32x4;
typedef __attribute__((ext_vector_type(16))) float f32x16;

#define NB 8
#define NC 512
#define HW 1024
#define NHEAD 8
#define DHEAD 64
#define GROUPS 32
#define CPG 16          // channels per group
#define QKV_N 1536

// global -> LDS direct copy, 16B per lane; lds base must be wave-uniform.
#define GLL16(gaddr, ldsaddr)                                                  \
    __builtin_amdgcn_global_load_lds(                                          \
        (const __attribute__((address_space(1))) unsigned*)(gaddr),            \
        (__attribute__((address_space(3))) unsigned*)(ldsaddr), 16, 0, 0)

// Scratch in device globals.
__device__ alignas(64) short g_xn[(size_t)8192 * 512];      // GN out, pixel-major [bs][c]
__device__ alignas(64) short g_qkv[(size_t)8192 * 1536];    // QKV GEMM out [bs][3C]
__device__ alignas(64) short g_vt[(size_t)64 * 64 * 1024];  // V^T [b*8+h][d][s]
__device__ alignas(64) short g_attno[(size_t)8192 * 512];   // attention out [bs][c]
__device__ alignas(64) short g_wqkv[(size_t)1536 * 512];    // w_qkv as bf16 [o][c]
__device__ alignas(64) short g_wout[(size_t)512 * 512];     // w_out as bf16 [o][c]

__device__ __forceinline__ float b2f(short h) {
    union { unsigned u; float f; } v;
    v.u = ((unsigned)(unsigned short)h) << 16;
    return v.f;
}
__device__ __forceinline__ short f2b(float f) {
    union { float f; unsigned u; } v;
    v.f = f;
    unsigned r = v.u + 0x7fff + ((v.u >> 16) & 1);   // RNE
    return (short)(r >> 16);
}

// ---------------------------------------------------------------------------
// Kernel 1: prep = GroupNorm (blocks 0..255) + weight conversion (256..319).
// ---------------------------------------------------------------------------
__global__ __launch_bounds__(256) void prep_kernel(
    const float* __restrict__ x, const float* __restrict__ gamma,
    const float* __restrict__ beta, const float* __restrict__ wqkv,
    const float* __restrict__ wout) {
    int tid = threadIdx.x;
    if (blockIdx.x >= 256) {                 // ---- weight conversion part
        int wb = blockIdx.x - 256;           // 0..63
        for (int i = wb * 256 + tid; i < 1536 * 512; i += 64 * 256) {
            float v = wqkv[i];
            // Q rows: fold 1/sqrt(d) AND log2(e) so attn P = 2^S (raw v_exp).
            if (i < 512 * 512) v *= 0.18033688011112042f;
            g_wqkv[i] = f2b(v);
        }
        for (int i = wb * 256 + tid; i < 512 * 512; i += 64 * 256)
            g_wout[i] = f2b(wout[i]);
        return;
    }
    // ---- GroupNorm part
    int b = blockIdx.x >> 5, g = blockIdx.x & 31;
    __shared__ alignas(16) short tile[CPG][HW];          // 32 KB
    __shared__ float red[2][4];
    __shared__ float sg[CPG], sb[CPG];
    if (tid < CPG) {
        int cg = g * CPG + tid;
        sg[tid] = gamma[cg];
        sb[tid] = beta[cg];
    }
    const float* xb = x + (size_t)b * NC * HW + (size_t)g * CPG * HW;
    float s1 = 0.f, s2 = 0.f;
    #pragma unroll
    for (int it = 0; it < 8; it++) {
        int idx = tid + it * 256;
        f32x4 v0 = *(const f32x4*)(xb + idx * 8);
        f32x4 v1 = *(const f32x4*)(xb + idx * 8 + 4);
        bf16x8 w;
        #pragma unroll
        for (int j = 0; j < 4; j++) {
            s1 += v0[j] + v1[j]; s2 += v0[j] * v0[j] + v1[j] * v1[j];
            w[j] = f2b(v0[j]); w[j + 4] = f2b(v1[j]);
        }
        *(bf16x8*)(&((short*)tile)[idx * 8]) = w;
    }
    #pragma unroll
    for (int off = 32; off; off >>= 1) { s1 += __shfl_xor(s1, off); s2 += __shfl_xor(s2, off); }
    int wid = tid >> 6;
    if ((tid & 63) == 0) { red[0][wid] = s1; red[1][wid] = s2; }
    __syncthreads();
    float t1 = red[0][0] + red[0][1] + red[0][2] + red[0][3];
    float t2 = red[1][0] + red[1][1] + red[1][2] + red[1][3];
    float mean = t1 * (1.f / 16384.f);
    float var  = t2 * (1.f / 16384.f) - mean * mean;
    float inv  = rsqrtf(var + 1e-5f);
    #pragma unroll
    for (int p = 0; p < 4; p++) {
        int s = tid * 4 + p;
        bf16x8 pk0, pk1;
        #pragma unroll
        for (int cc = 0; cc < 8; cc++) {
            pk0[cc] = f2b((b2f(tile[cc][s])     - mean) * inv * sg[cc]     + sb[cc]);
            pk1[cc] = f2b((b2f(tile[cc + 8][s]) - mean) * inv * sg[cc + 8] + sb[cc + 8]);
        }
        size_t dst = ((size_t)(b * HW + s)) * NC + g * CPG;
        *(bf16x8*)(g_xn + dst)     = pk0;
        *(bf16x8*)(g_xn + dst + 8) = pk1;
    }
}

// ---------------------------------------------------------------------------
// Kernel 2: QKV GEMM. M=8192 N=1536 K=512. BK=64 + XOR swizzle (r18).
// ---------------------------------------------------------------------------
__global__ __launch_bounds__(256) void gemm_qkv() {
    const int K = NC;
    int tid = threadIdx.x, lane = tid & 63, wid = tid >> 6;
    int quad = lane >> 4, l15 = lane & 15;
    int row0 = blockIdx.x * 128;
    int col0 = blockIdx.y * 128;
    __shared__ alignas(16) short sa[128 * 64];   // 16 KB, granule-swizzled
    __shared__ alignas(16) short sbuf[128 * 64]; // 16 KB, granule-swizzled
    int r_lo = lane >> 3;                        // row within 8-row stripe
    int s_log = (lane & 7) ^ r_lo;               // pre-swizzled source granule
    int swz = l15 & 7;                           // fragment-read swizzle
    const short* ga = g_xn   + (size_t)(row0 + wid * 32 + r_lo) * K + s_log * 8;
    const short* gb = g_wqkv + (size_t)(col0 + wid * 32 + r_lo) * K + s_log * 8;
    int mw = (wid >> 1) * 64, nw = (wid & 1) * 64;
    f32x4 acc[4][4] = {};
    for (int k = 0; k < K; k += 64) {
        #pragma unroll
        for (int c = 0; c < 4; c++) {
            GLL16(ga + (size_t)(c * 8) * K + k, &sa[(wid * 32 + c * 8) * 64]);
            GLL16(gb + (size_t)(c * 8) * K + k, &sbuf[(wid * 32 + c * 8) * 64]);
        }
        __syncthreads();
        bf16x8 af0[4], af1[4], bf0[4], bf1[4];
        #pragma unroll
        for (int m = 0; m < 4; m++) {
            int row = mw + m * 16 + l15;
            af0[m] = *(const bf16x8*)&sa[row * 64 + ((quad ^ swz) * 8)];
            af1[m] = *(const bf16x8*)&sa[row * 64 + (((4 + quad) ^ swz) * 8)];
        }
        #pragma unroll
        for (int n = 0; n < 4; n++) {
            int row = nw + n * 16 + l15;
            bf0[n] = *(const bf16x8*)&sbuf[row * 64 + ((quad ^ swz) * 8)];
            bf1[n] = *(const bf16x8*)&sbuf[row * 64 + (((4 + quad) ^ swz) * 8)];
        }
        #pragma unroll
        for (int m = 0; m < 4; m++)
            #pragma unroll
            for (int n = 0; n < 4; n++) {
                acc[m][n] = __builtin_amdgcn_mfma_f32_16x16x32_bf16(af0[m], bf0[n], acc[m][n], 0, 0, 0);
                acc[m][n] = __builtin_amdgcn_mfma_f32_16x16x32_bf16(af1[m], bf1[n], acc[m][n], 0, 0, 0);
            }
        __syncthreads();
    }
    #pragma unroll
    for (int m = 0; m < 4; m++)
        #pragma unroll
        for (int n = 0; n < 4; n++)
            #pragma unroll
            for (int r = 0; r < 4; r++) {
                int row = row0 + mw + m * 16 + quad * 4 + r;
                int col = col0 + nw + n * 16 + l15;
                g_qkv[(size_t)row * QKV_N + col] = f2b(acc[m][n][r]);
            }
}

// ---------------------------------------------------------------------------
// Kernel 2b: V transpose. g_qkv V-part [bs][c] -> g_vt[bh][d][s].
// ---------------------------------------------------------------------------
__global__ __launch_bounds__(256) void transpose_v() {
    int bh = blockIdx.x & 63, st = blockIdx.x >> 6;     // grid 1024
    int b = bh >> 3, h = bh & 7;
    int tid = threadIdx.x;
    __shared__ alignas(16) short tile[64][72];
    int s0 = st * 64;
    #pragma unroll
    for (int cc = 0; cc < 2; cc++) {
        int idx = tid + cc * 256;
        int s = idx >> 3, dc = idx & 7;
        *(bf16x8*)&tile[s][dc * 8] =
            *(const bf16x8*)(g_qkv + ((size_t)(b * HW + s0 + s)) * QKV_N + 1024 + h * DHEAD + dc * 8);
    }
    __syncthreads();
    #pragma unroll
    for (int cc = 0; cc < 2; cc++) {
        int idx = tid + cc * 256;
        int d = idx & 63, sc = idx >> 6;                // sc wave-uniform
        bf16x8 o;
        #pragma unroll
        for (int j = 0; j < 8; j++) o[j] = tile[sc * 8 + j][d];
        *(bf16x8*)(g_vt + ((size_t)(bh * 64 + d)) * HW + s0 + sc * 8) = o;
    }
}

// ---------------------------------------------------------------------------
// Kernel 3: flash attention, 32x32-MFMA + T15 double-pipeline (r24/r25).
// Grid 512: bh = blk&63 (XCD L2 sharing), qt = blk>>6 (0..7).
// 4 waves x 32 q-rows. P lane-local via 32x32 D-layout; cvt_pk+permlane32
// build PV A-frags in regs (ap_cur/ap_next). Body(it): bv->regs, sync,
// stage(it+2), QK(it+1), exp->ap_next || l+PV(it) from ap_cur.
// LDS: kt 2x8 + vt 2x8 = 32KB.
// ---------------------------------------------------------------------------
__global__ __launch_bounds__(256) void attn_kernel() {
    int bh = blockIdx.x & 63, qt = blockIdx.x >> 6;
    int b = bh >> 3, h = bh & 7;
    int tid = threadIdx.x, lane = tid & 63, wid = tid >> 6;
    int l31 = lane & 31, hl = lane >> 5;
    __shared__ alignas(16) short kt[2][64 * 64];    // 8 KB each, swizzled
    __shared__ alignas(16) short vt[2][64 * 64];    // 8 KB each, swizzled
    int qrow0 = qt * 128 + wid * 32;

    // Q = B-operand: B[k=d][j=m]: lane j=l31, k = ks*16 + hl*8 + jj.
    const short* qb = g_qkv + ((size_t)(b * HW + qrow0 + l31)) * QKV_N + h * DHEAD + hl * 8;
    bf16x8 aq[4];
    #pragma unroll
    for (int ks = 0; ks < 4; ks++) aq[ks] = *(const bf16x8*)(qb + ks * 16);

    f32x16 acc_o0 = {}, acc_o1 = {}, acc_l = {};
    bf16x8 vone;
    #pragma unroll
    for (int j = 0; j < 8; j++) vone[j] = (short)0x3f80;   // bf16 1.0

    int r_lo = lane >> 3;
    int s_log = (lane & 7) ^ r_lo;

    auto stage = [&](int it, int bufi) {
        int t0 = it * 64;
        #pragma unroll
        for (int c = 0; c < 2; c++) {
            int r = wid * 16 + c * 8 + r_lo;
            GLL16(g_qkv + ((size_t)(b * HW + t0 + r)) * QKV_N + 512 + h * DHEAD + s_log * 8,
                  &kt[bufi][(wid * 16 + c * 8) * 64]);
            GLL16(g_vt + ((size_t)(bh * 64 + r)) * HW + t0 + s_log * 8,
                  &vt[bufi][(wid * 16 + c * 8) * 64]);
        }
    };

    // QK of the tile in kt[buf]: z[th] = K x Q (32x32x16), m = lane&31.
    auto qk = [&](int buf, f32x16& z0, f32x16& z1) {
        #pragma unroll
        for (int ks = 0; ks < 4; ks++) {
            int g0 = ks * 2 + hl;                    // logical d-granule
            int rowa = l31;                          // t 0..31
            bf16x8 k0 = *(const bf16x8*)&kt[buf][rowa * 64 + ((g0 ^ (rowa & 7)) * 8)];
            z0 = __builtin_amdgcn_mfma_f32_32x32x16_bf16(k0, aq[ks], z0, 0, 0, 0);
            int rowb = 32 + l31;                     // t 32..63
            bf16x8 k1 = *(const bf16x8*)&kt[buf][rowb * 64 + ((g0 ^ (rowb & 7)) * 8)];
            z1 = __builtin_amdgcn_mfma_f32_32x32x16_bf16(k1, aq[ks], z1, 0, 0, 0);
        }
    };

    // P = 2^z, cvt_pk + 8 permlane32_swap -> PV A-frags ap[4] (verified r23).
    auto exppack = [&](const f32x16& z0, const f32x16& z1, bf16x8* ap) {
        unsigned u0[8], u1[8];
        #pragma unroll
        for (int p = 0; p < 8; p++) {
            float e0, e1, e2, e3;
            asm("v_exp_f32 %0, %1" : "=v"(e0) : "v"(z0[2 * p]));
            asm("v_exp_f32 %0, %1" : "=v"(e1) : "v"(z0[2 * p + 1]));
            asm("v_exp_f32 %0, %1" : "=v"(e2) : "v"(z1[2 * p]));
            asm("v_exp_f32 %0, %1" : "=v"(e3) : "v"(z1[2 * p + 1]));
            asm("v_cvt_pk_bf16_f32 %0, %1, %2" : "=v"(u0[p]) : "v"(e0), "v"(e1));
            asm("v_cvt_pk_bf16_f32 %0, %1, %2" : "=v"(u1[p]) : "v"(e2), "v"(e3));
        }
        #pragma unroll
        for (int th = 0; th < 2; th++) {
            #pragma unroll
            for (int ks1 = 0; ks1 < 2; ks1++) {
                unsigned x0 = th ? u1[4 * ks1]     : u0[4 * ks1];
                unsigned y0 = th ? u1[4 * ks1 + 2] : u0[4 * ks1 + 2];
                unsigned x1 = th ? u1[4 * ks1 + 1] : u0[4 * ks1 + 1];
                unsigned y1 = th ? u1[4 * ks1 + 3] : u0[4 * ks1 + 3];
                asm("v_permlane32_swap_b32 %0, %1" : "+v"(x0), "+v"(y0));
                asm("v_permlane32_swap_b32 %0, %1" : "+v"(x1), "+v"(y1));
                union { unsigned w[4]; bf16x8 v; } pa;
                pa.w[0] = x0; pa.w[1] = x1; pa.w[2] = y0; pa.w[3] = y1;
                ap[th * 2 + ks1] = pa.v;
            }
        }
    };

    // Prologue: two tiles in flight; P(0) in regs.
    stage(0, 0);
    __syncthreads();
    stage(1, 1);
    bf16x8 ap_cur[4];
    {
        f32x16 z0 = {}, z1 = {};
        qk(0, z0, z1);
        exppack(z0, z1, ap_cur);
    }

    for (int it = 0; it < 15; it++) {
        int cur = it & 1, alt = cur ^ 1;
        // ---- V(it) into regs BEFORE the barrier ----
        bf16x8 bv0[4], bv1[4];
        #pragma unroll
        for (int ks = 0; ks < 4; ks++) {
            int gt = ks * 2 + hl;                    // logical t-granule
            int rowd0 = l31;                         // d 0..31
            bv0[ks] = *(const bf16x8*)&vt[cur][rowd0 * 64 + ((gt ^ (rowd0 & 7)) * 8)];
            int rowd1 = 32 + l31;                    // d 32..63
            bv1[ks] = *(const bf16x8*)&vt[cur][rowd1 * 64 + ((gt ^ (rowd1 & 7)) * 8)];
        }
        __syncthreads();              // stage(it+1) landed; all buf-cur reads done
        if (it < 14) stage(it + 2, cur);   // reuse buf cur (contents now in regs)
        // ---- QK(it+1) + exp -> ap_next (VALU) || l+PV(it) (MFMA) ----
        f32x16 z0 = {}, z1 = {};
        qk(alt, z0, z1);
        bf16x8 ap_next[4];
        exppack(z0, z1, ap_next);
        #pragma unroll
        for (int ks = 0; ks < 4; ks++)
            acc_l = __builtin_amdgcn_mfma_f32_32x32x16_bf16(ap_cur[ks], vone, acc_l, 0, 0, 0);
        #pragma unroll
        for (int ks = 0; ks < 4; ks++) {
            acc_o0 = __builtin_amdgcn_mfma_f32_32x32x16_bf16(ap_cur[ks], bv0[ks], acc_o0, 0, 0, 0);
            acc_o1 = __builtin_amdgcn_mfma_f32_32x32x16_bf16(ap_cur[ks], bv1[ks], acc_o1, 0, 0, 0);
        }
        #pragma unroll
        for (int ks = 0; ks < 4; ks++) ap_cur[ks] = ap_next[ks];
    }
    // ---- epilogue tile 15: ap_cur = P(15); V in vt[1] (staged, synced) ----
    {
        #pragma unroll
        for (int ks = 0; ks < 4; ks++)
            acc_l = __builtin_amdgcn_mfma_f32_32x32x16_bf16(ap_cur[ks], vone, acc_l, 0, 0, 0);
        #pragma unroll
        for (int ks = 0; ks < 4; ks++) {
            int gt = ks * 2 + hl;
            int rowd0 = l31;
            bf16x8 bv0 = *(const bf16x8*)&vt[1][rowd0 * 64 + ((gt ^ (rowd0 & 7)) * 8)];
            acc_o0 = __builtin_amdgcn_mfma_f32_32x32x16_bf16(ap_cur[ks], bv0, acc_o0, 0, 0, 0);
            int rowd1 = 32 + l31;
            bf16x8 bv1 = *(const bf16x8*)&vt[1][rowd1 * 64 + ((gt ^ (rowd1 & 7)) * 8)];
            acc_o1 = __builtin_amdgcn_mfma_f32_32x32x16_bf16(ap_cur[ks], bv1, acc_o1, 0, 0, 0);
        }
    }
    // Epilogue: m = (r&3)+8*(r>>2)+4*hl; l in acc_l[r] (same layout).
    #pragma unroll
    for (int r = 0; r < 16; r++) {
        int m = (r & 3) + 8 * (r >> 2) + 4 * hl;
        float invl = 1.f / acc_l[r];
        size_t row = (size_t)(b * HW + qrow0 + m);
        g_attno[row * NC + h * DHEAD + l31]      = f2b(acc_o0[r] * invl);
        g_attno[row * NC + h * DHEAD + 32 + l31] = f2b(acc_o1[r] * invl);
    }
}

// ---------------------------------------------------------------------------
// Kernel 4: out-proj GEMM + residual, m97 structure. (R16 version)
// ---------------------------------------------------------------------------
__global__ __launch_bounds__(256) void gemm_out(
    const float* __restrict__ xres, float* __restrict__ out) {
    const int K = NC;
    int tid = threadIdx.x, lane = tid & 63, wid = tid >> 6;
    int quad = lane >> 4, l15 = lane & 15;
    int row0 = blockIdx.x * 128;   // o
    int col0 = blockIdx.y * 128;   // bs
    __shared__ alignas(16) short sa[128 * 32];
    __shared__ alignas(16) short sbuf[128 * 32];
    int srow = wid * 32 + (lane >> 2);
    int scol = (lane & 3) * 8;
    const short* ga = g_wout  + (size_t)(row0 + srow) * K + scol;
    const short* gb = g_attno + (size_t)(col0 + srow) * K + scol;
    short* la = sa   + wid * 1024;
    short* lb = sbuf + wid * 1024;
    int mw = (wid >> 1) * 64, nw = (wid & 1) * 64;
    f32x4 acc[4][4] = {};
    for (int k = 0; k < K; k += 32) {
        GLL16(ga + k, la);
        GLL16(ga + (size_t)16 * K + k, la + 512);
        GLL16(gb + k, lb);
        GLL16(gb + (size_t)16 * K + k, lb + 512);
        __syncthreads();
        bf16x8 af[4], bfv[4];
        #pragma unroll
        for (int m = 0; m < 4; m++) af[m]  = *(const bf16x8*)&sa[(mw + m * 16 + l15) * 32 + quad * 8];
        #pragma unroll
        for (int n = 0; n < 4; n++) bfv[n] = *(const bf16x8*)&sbuf[(nw + n * 16 + l15) * 32 + quad * 8];
        #pragma unroll
        for (int m = 0; m < 4; m++)
            #pragma unroll
            for (int n = 0; n < 4; n++)
                acc[m][n] = __builtin_amdgcn_mfma_f32_16x16x32_bf16(af[m], bfv[n], acc[m][n], 0, 0, 0);
        __syncthreads();
    }
    #pragma unroll
    for (int m = 0; m < 4; m++)
        #pragma unroll
        for (int n = 0; n < 4; n++)
            #pragma unroll
            for (int r = 0; r < 4; r++) {
                int o  = row0 + mw + m * 16 + quad * 4 + r;
                int bs = col0 + nw + n * 16 + l15;
                size_t addr = (size_t)(bs >> 10) * ((size_t)NC * HW) + (size_t)o * HW + (bs & 1023);
                out[addr] = acc[m][n][r] + xres[addr];
            }
}

// ---------------------------------------------------------------------------
extern "C" void kernel_launch(void* const* d_in, const int* in_sizes, int n_in,
                              void* d_out, int out_size, void* d_ws, size_t ws_size,
                              hipStream_t stream) {
    const float* x     = (const float*)d_in[0];
    const float* gamma = (const float*)d_in[1];
    const float* beta  = (const float*)d_in[2];
    const float* wqkv  = (const float*)d_in[3];
    const float* wout  = (const float*)d_in[4];
    float* out = (float*)d_out;

    prep_kernel<<<dim3(320), dim3(256), 0, stream>>>(x, gamma, beta, wqkv, wout);
    gemm_qkv<<<dim3(64, 12), dim3(256), 0, stream>>>();
    transpose_v<<<dim3(1024), dim3(256), 0, stream>>>();
    attn_kernel<<<dim3(512), dim3(256), 0, stream>>>();
    gemm_out<<<dim3(4, 64), dim3(256), 0, stream>>>(x, out);
}